// Round 9
// baseline (80.531 us; speedup 1.0000x reference)
//
#include <hip/hip_runtime.h>

// 5x5 median filter, reflect padding, per-channel, [16,3,256,256] f32.
// 4 pixels/lane, packed f16 (v_pk_min/max_f16), branchless edges.
// Round 9: load restructure — the 8 needed columns [w0-2, w0+5] are loaded
// as TWO dword-aligned float4 (gfx9+ allows 4B-aligned dwordx4) instead of
// three 16B-aligned ones: 10 VMEM/quad vs 15, no dead register halves.
// Median network unchanged (sorted columns + Batcher merges + rank-prune).
// Output bit-identical to rounds 4-8 (absmax 0.00390625).

#define HH 256
#define WW 256

typedef __fp16 f16x2 __attribute__((ext_vector_type(2)));
// 4B-aligned float4 so clang emits a single dwordx4 at dword alignment.
typedef float f32x4u __attribute__((ext_vector_type(4), aligned(4)));

__device__ __forceinline__ f16x2 mn(f16x2 a, f16x2 b) { return __builtin_elementwise_min(a, b); }
__device__ __forceinline__ f16x2 mx(f16x2 a, f16x2 b) { return __builtin_elementwise_max(a, b); }

__device__ __forceinline__ void ce(f16x2 &a, f16x2 &b) {
    f16x2 lo = mn(a, b);
    f16x2 hi = mx(a, b);
    a = lo; b = hi;
}

// Knuth 9-comparator sort of 5 (ascending, in place).
__device__ __forceinline__ void sort5(f16x2* c) {
    ce(c[0],c[1]); ce(c[3],c[4]); ce(c[2],c[4]); ce(c[2],c[3]);
    ce(c[0],c[3]); ce(c[0],c[2]); ce(c[1],c[4]); ce(c[1],c[3]); ce(c[1],c[2]);
}

// Batcher odd-even merges of ascending sorted lists (all indices static).
__device__ __forceinline__ void m11(const f16x2* A, const f16x2* B, f16x2* Z) {
    Z[0] = mn(A[0], B[0]); Z[1] = mx(A[0], B[0]);
}

__device__ __forceinline__ void m21(const f16x2* A, const f16x2* B, f16x2* Z) {
    f16x2 E[2]; m11(A, B, E);              // evens: A0 | B0
    Z[0] = E[0];                           // odd: A1
    Z[1] = mn(A[1], E[1]); Z[2] = mx(A[1], E[1]);
}

__device__ __forceinline__ void m22(const f16x2* A, const f16x2* B, f16x2* Z) {
    f16x2 e0 = A[0], e1 = B[0]; ce(e0, e1);
    f16x2 o0 = A[1], o1 = B[1]; ce(o0, o1);
    Z[0] = e0; f16x2 p = o0, q = e1; ce(p, q); Z[1] = p; Z[2] = q; Z[3] = o1;
}

__device__ __forceinline__ void m32(const f16x2* A, const f16x2* B, f16x2* Z) {
    f16x2 Ae[2] = {A[0], A[2]}, E[3];
    m21(Ae, B, E);                         // evens: A0,A2 | B0
    f16x2 O[2]; f16x2 Ao[1] = {A[1]}, Bo[1] = {B[1]};
    m11(Ao, Bo, O);                        // odds: A1 | B1
    Z[0] = E[0];
    Z[1] = mn(O[0], E[1]); Z[2] = mx(O[0], E[1]);
    Z[3] = mn(O[1], E[2]); Z[4] = mx(O[1], E[2]);
}

__device__ __forceinline__ void m33(const f16x2* A, const f16x2* B, f16x2* Z) {
    f16x2 Ae[2] = {A[0], A[2]}, Be[2] = {B[0], B[2]}, E[4];
    m22(Ae, Be, E);
    f16x2 o0 = A[1], o1 = B[1]; ce(o0, o1);
    Z[0] = E[0];
    f16x2 p = o0, q = E[1]; ce(p, q); Z[1] = p; Z[2] = q;
    p = o1; q = E[2]; ce(p, q); Z[3] = p; Z[4] = q;
    Z[5] = E[3];
}

__device__ __forceinline__ void m55(const f16x2* A, const f16x2* B, f16x2* Z) {
    f16x2 Ae[3] = {A[0], A[2], A[4]}, Be[3] = {B[0], B[2], B[4]}, E[6];
    m33(Ae, Be, E);
    f16x2 Ao[2] = {A[1], A[3]}, Bo[2] = {B[1], B[3]}, O[4];
    m22(Ao, Bo, O);
    Z[0] = E[0];
#pragma unroll
    for (int i = 0; i < 4; ++i) {
        f16x2 p = O[i], q = E[i+1]; ce(p, q); Z[2*i+1] = p; Z[2*i+2] = q;
    }
    Z[9] = E[5];
}

__device__ __forceinline__ void m1010(const f16x2* S, const f16x2* T, f16x2* Z) {
    f16x2 Se[5] = {S[0],S[2],S[4],S[6],S[8]}, Te[5] = {T[0],T[2],T[4],T[6],T[8]}, E[10];
    m55(Se, Te, E);
    f16x2 So[5] = {S[1],S[3],S[5],S[7],S[9]}, To[5] = {T[1],T[3],T[5],T[7],T[9]}, O[10];
    m55(So, To, O);
    Z[0] = E[0];
#pragma unroll
    for (int i = 0; i < 9; ++i) {
        f16x2 p = O[i], q = E[i+1]; ce(p, q); Z[2*i+1] = p; Z[2*i+2] = q;
    }
    Z[19] = O[9];
}

// rank-5 (0-indexed) of merge(U6 sorted, c5 sorted) == median of the 11.
// Only Z[5]=min(O[2],E[3]) consumed -> DCE keeps ~10 CEs, depth ~4.
__device__ __forceinline__ f16x2 sel5_65(const f16x2* U, const f16x2* c) {
    f16x2 Ue[3] = {U[0], U[2], U[4]}, ce_[3] = {c[0], c[2], c[4]}, E[6];
    m33(Ue, ce_, E);
    f16x2 Uo[3] = {U[1], U[3], U[5]}, co[2] = {c[1], c[3]}, O[5];
    m32(Uo, co, O);
    return mn(O[2], E[3]);
}

__global__ void __launch_bounds__(256) median5_q(const float* __restrict__ in,
                                                 float4* __restrict__ out,
                                                 int nquads) {
    int idx = blockIdx.x * blockDim.x + threadIdx.x;
    if (idx >= nquads) return;

    int w0 = (idx & (WW/4 - 1)) << 2;
    int h  = (idx >> 6) & (HH - 1);
    int plane = idx >> 14;
    const float* p = in + (size_t)plane * (HH * WW);

    int rr[5];
#pragma unroll
    for (int d = 0; d < 5; ++d) {
        int r = h + d - 2;
        r = (r < 0) ? -r : r;
        r = (r >= HH) ? (2*HH - 2 - r) : r;
        rr[d] = r * WW;
    }

    const bool left  = (w0 == 0);
    const bool right = (w0 == WW - 4);
    // Two dword-aligned float4 blocks covering cols [w0-2, w0+5].
    // Left lane clamps A to col 0; right lane clamps B to col WW-4.
    const int aBase = left  ? 0        : (w0 - 2);
    const int bBase = right ? (WW - 4) : (w0 + 2);

    // Packed columns pc[j][row]: pc[j] = pk(x_j, x_{j+1}), x_k = col w0-2+k.
    // Pair A (px w0,w0+1) cols = pc0..4; pair B (px w0+2,w0+3) = pc2..6.
    f16x2 pc[7][5];
#pragma unroll
    for (int i = 0; i < 5; ++i) {
        const float* prow = p + rr[i];
        f32x4u A = *(const f32x4u*)(prow + aBase);
        f32x4u B = *(const f32x4u*)(prow + bBase);
        // normal: x_k = {A.x,A.y,A.z,A.w,B.x,B.y,B.z,B.w}
        float x0 = A.x, x1 = A.y, x2 = A.z, x3 = A.w;
        float x4 = B.x, x5 = B.y, x6 = B.z, x7 = B.w;
        // left (w0==0, A=cols 0..3, B=cols 2..5): taps = cols[2,1,0,1,2,3,4,5]
        x0 = left ? A.z : x0;
        x2 = left ? A.x : x2;
        x3 = left ? A.y : x3;
        x4 = left ? A.z : x4;
        x5 = left ? A.w : x5;
        // right (w0==252, B=cols 252..255): x4=col254=B.z, x5=255=B.w, x7=253=B.y
        x4 = right ? B.z : x4;
        x5 = right ? B.w : x5;
        x7 = right ? B.y : x7;

        pc[0][i] = __builtin_amdgcn_cvt_pkrtz(x0, x1);
        pc[1][i] = __builtin_amdgcn_cvt_pkrtz(x1, x2);
        pc[2][i] = __builtin_amdgcn_cvt_pkrtz(x2, x3);
        pc[3][i] = __builtin_amdgcn_cvt_pkrtz(x3, x4);
        pc[4][i] = __builtin_amdgcn_cvt_pkrtz(x4, x5);
        pc[5][i] = __builtin_amdgcn_cvt_pkrtz(x5, x6);
        pc[6][i] = __builtin_amdgcn_cvt_pkrtz(x6, x7);
    }

#pragma unroll
    for (int j = 0; j < 7; ++j) sort5(pc[j]);

    f16x2 S01[10], T23[10], S56[10];
    m55(pc[0], pc[1], S01);
    m55(pc[2], pc[3], T23);   // shared between pairs
    m55(pc[5], pc[6], S56);

    // Sorted 20 per pair; only ranks 7..12 consumed (rank-prune) -> DCE.
    f16x2 UA[20], UB[20];
    m1010(S01, T23, UA);
    f16x2 mA = sel5_65(&UA[7], pc[4]);
    m1010(S56, T23, UB);
    f16x2 mB = sel5_65(&UB[7], pc[4]);

    out[idx] = make_float4((float)mA[0], (float)mA[1], (float)mB[0], (float)mB[1]);
}

extern "C" void kernel_launch(void* const* d_in, const int* in_sizes, int n_in,
                              void* d_out, int out_size, void* d_ws, size_t ws_size,
                              hipStream_t stream) {
    const float* image = (const float*)d_in[0];
    float4* out = (float4*)d_out;
    int nquads = in_sizes[0] / 4;
    int block = 256;
    int grid = (nquads + block - 1) / block;
    median5_q<<<grid, block, 0, stream>>>(image, out, nquads);
}

// Round 10
// 76.576 us; speedup vs baseline: 1.0516x; 1.0516x over previous
//
#include <hip/hip_runtime.h>

// 5x5 median filter, reflect padding, per-channel, [16,3,256,256] f32.
// Round 10: EIGHT pixels/lane (4 packed-f16 pairs A..D) to amortize fixed
// per-lane costs (reflect, addressing) and share sort/merge work:
//   11 column sort5 (vs 14 for 2 quads), 5 m55 (vs 6), 4 m1010[7..12] + sel.
//   4 aligned float4 loads/row (vs 6), edge handling = 2 cndmask/row.
// Median network per pair identical to round 8 (verified bit-exact).
// Output bit-identical to rounds 4-9 (absmax 0.00390625).

#define HH 256
#define WW 256

typedef __fp16 f16x2 __attribute__((ext_vector_type(2)));

__device__ __forceinline__ f16x2 mn(f16x2 a, f16x2 b) { return __builtin_elementwise_min(a, b); }
__device__ __forceinline__ f16x2 mx(f16x2 a, f16x2 b) { return __builtin_elementwise_max(a, b); }

__device__ __forceinline__ void ce(f16x2 &a, f16x2 &b) {
    f16x2 lo = mn(a, b);
    f16x2 hi = mx(a, b);
    a = lo; b = hi;
}

// Knuth 9-comparator sort of 5 (ascending, in place).
__device__ __forceinline__ void sort5(f16x2* c) {
    ce(c[0],c[1]); ce(c[3],c[4]); ce(c[2],c[4]); ce(c[2],c[3]);
    ce(c[0],c[3]); ce(c[0],c[2]); ce(c[1],c[4]); ce(c[1],c[3]); ce(c[1],c[2]);
}

// Batcher odd-even merges of ascending sorted lists (all indices static).
__device__ __forceinline__ void m11(const f16x2* A, const f16x2* B, f16x2* Z) {
    Z[0] = mn(A[0], B[0]); Z[1] = mx(A[0], B[0]);
}

__device__ __forceinline__ void m21(const f16x2* A, const f16x2* B, f16x2* Z) {
    f16x2 E[2]; m11(A, B, E);
    Z[0] = E[0];
    Z[1] = mn(A[1], E[1]); Z[2] = mx(A[1], E[1]);
}

__device__ __forceinline__ void m22(const f16x2* A, const f16x2* B, f16x2* Z) {
    f16x2 e0 = A[0], e1 = B[0]; ce(e0, e1);
    f16x2 o0 = A[1], o1 = B[1]; ce(o0, o1);
    Z[0] = e0; f16x2 p = o0, q = e1; ce(p, q); Z[1] = p; Z[2] = q; Z[3] = o1;
}

__device__ __forceinline__ void m32(const f16x2* A, const f16x2* B, f16x2* Z) {
    f16x2 Ae[2] = {A[0], A[2]}, E[3];
    m21(Ae, B, E);
    f16x2 O[2]; f16x2 Ao[1] = {A[1]}, Bo[1] = {B[1]};
    m11(Ao, Bo, O);
    Z[0] = E[0];
    Z[1] = mn(O[0], E[1]); Z[2] = mx(O[0], E[1]);
    Z[3] = mn(O[1], E[2]); Z[4] = mx(O[1], E[2]);
}

__device__ __forceinline__ void m33(const f16x2* A, const f16x2* B, f16x2* Z) {
    f16x2 Ae[2] = {A[0], A[2]}, Be[2] = {B[0], B[2]}, E[4];
    m22(Ae, Be, E);
    f16x2 o0 = A[1], o1 = B[1]; ce(o0, o1);
    Z[0] = E[0];
    f16x2 p = o0, q = E[1]; ce(p, q); Z[1] = p; Z[2] = q;
    p = o1; q = E[2]; ce(p, q); Z[3] = p; Z[4] = q;
    Z[5] = E[3];
}

__device__ __forceinline__ void m55(const f16x2* A, const f16x2* B, f16x2* Z) {
    f16x2 Ae[3] = {A[0], A[2], A[4]}, Be[3] = {B[0], B[2], B[4]}, E[6];
    m33(Ae, Be, E);
    f16x2 Ao[2] = {A[1], A[3]}, Bo[2] = {B[1], B[3]}, O[4];
    m22(Ao, Bo, O);
    Z[0] = E[0];
#pragma unroll
    for (int i = 0; i < 4; ++i) {
        f16x2 p = O[i], q = E[i+1]; ce(p, q); Z[2*i+1] = p; Z[2*i+2] = q;
    }
    Z[9] = E[5];
}

__device__ __forceinline__ void m1010(const f16x2* S, const f16x2* T, f16x2* Z) {
    f16x2 Se[5] = {S[0],S[2],S[4],S[6],S[8]}, Te[5] = {T[0],T[2],T[4],T[6],T[8]}, E[10];
    m55(Se, Te, E);
    f16x2 So[5] = {S[1],S[3],S[5],S[7],S[9]}, To[5] = {T[1],T[3],T[5],T[7],T[9]}, O[10];
    m55(So, To, O);
    Z[0] = E[0];
#pragma unroll
    for (int i = 0; i < 9; ++i) {
        f16x2 p = O[i], q = E[i+1]; ce(p, q); Z[2*i+1] = p; Z[2*i+2] = q;
    }
    Z[19] = O[9];
}

// rank-5 (0-indexed) of merge(U6 sorted, c5 sorted) == median of the 11.
// Only Z[5]=min(O[2],E[3]) consumed -> DCE keeps ~10 CEs, depth ~4.
__device__ __forceinline__ f16x2 sel5_65(const f16x2* U, const f16x2* c) {
    f16x2 Ue[3] = {U[0], U[2], U[4]}, ce_[3] = {c[0], c[2], c[4]}, E[6];
    m33(Ue, ce_, E);
    f16x2 Uo[3] = {U[1], U[3], U[5]}, co[2] = {c[1], c[3]}, O[5];
    m32(Uo, co, O);
    return mn(O[2], E[3]);
}

// Median of pair: merged 4 columns (M,N) + fifth sorted column f.
__device__ __forceinline__ f16x2 pair_median(const f16x2* M, const f16x2* N,
                                             const f16x2* f) {
    f16x2 U[20];
    m1010(M, N, U);                 // only ranks 7..12 survive DCE
    return sel5_65(&U[7], f);
}

__global__ void __launch_bounds__(256) median5_o(const float* __restrict__ in,
                                                 float4* __restrict__ out,
                                                 int nocts) {
    int idx = blockIdx.x * blockDim.x + threadIdx.x;
    if (idx >= nocts) return;

    int w0 = (idx & (WW/8 - 1)) << 3;   // first pixel column of the octet
    int h  = (idx >> 5) & (HH - 1);
    int plane = idx >> 13;              // 8192 octets per plane
    const float* p = in + (size_t)plane * (HH * WW);

    int rr[5];
#pragma unroll
    for (int d = 0; d < 5; ++d) {
        int r = h + d - 2;
        r = (r < 0) ? -r : r;
        r = (r >= HH) ? (2*HH - 2 - r) : r;
        rr[d] = r * WW;
    }

    const bool left  = (w0 == 0);
    const bool right = (w0 == WW - 8);
    // Four 16B-aligned float4 blocks covering cols [w0-4, w0+12).
    // left: clamp b0 to col 0 -> reflect taps col2=b0.z (auto), col1=b0.y.
    // right: clamp b3 to col WW-4 -> reflect taps 254=b3.z, 253=b3.y (auto).
    const int b0base = left  ? 0        : (w0 - 4);
    const int b3base = right ? (WW - 4) : (w0 + 8);

    // x_k = input col w0-2+k, k=0..11. pc[j] = pk(x_j, x_{j+1}), j=0..10.
    // Pairs: A(px w0,w0+1)=pc0..4, B=pc2..6, C=pc4..8, D=pc6..10.
    f16x2 pc[11][5];
#pragma unroll
    for (int i = 0; i < 5; ++i) {
        const float* prow = p + rr[i];
        float4 b0 = *(const float4*)(prow + b0base);
        float4 b1 = *(const float4*)(prow + w0);
        float4 b2 = *(const float4*)(prow + w0 + 4);
        float4 b3 = *(const float4*)(prow + b3base);
        float x0  = b0.z;                      // left: col2=reflect(-2) auto
        float x1  = left  ? b0.y : b0.w;       // left: col1=reflect(-1)
        float x2  = b1.x, x3 = b1.y, x4 = b1.z, x5 = b1.w;
        float x6  = b2.x, x7 = b2.y, x8 = b2.z, x9 = b2.w;
        float x10 = right ? b3.z : b3.x;       // right: 254=reflect(256)
        float x11 = b3.y;                      // right: 253=reflect(257) auto
        pc[0][i]  = __builtin_amdgcn_cvt_pkrtz(x0, x1);
        pc[1][i]  = __builtin_amdgcn_cvt_pkrtz(x1, x2);
        pc[2][i]  = __builtin_amdgcn_cvt_pkrtz(x2, x3);
        pc[3][i]  = __builtin_amdgcn_cvt_pkrtz(x3, x4);
        pc[4][i]  = __builtin_amdgcn_cvt_pkrtz(x4, x5);
        pc[5][i]  = __builtin_amdgcn_cvt_pkrtz(x5, x6);
        pc[6][i]  = __builtin_amdgcn_cvt_pkrtz(x6, x7);
        pc[7][i]  = __builtin_amdgcn_cvt_pkrtz(x7, x8);
        pc[8][i]  = __builtin_amdgcn_cvt_pkrtz(x8, x9);
        pc[9][i]  = __builtin_amdgcn_cvt_pkrtz(x9, x10);
        pc[10][i] = __builtin_amdgcn_cvt_pkrtz(x10, x11);
    }

#pragma unroll
    for (int j = 0; j < 11; ++j) sort5(pc[j]);

    // Shared merged column-pairs: A,B share M23; B,C share M56; C,D share M78.
    f16x2 M01[10], M23[10], M56[10], M78[10], M910[10];
    m55(pc[0], pc[1], M01);
    m55(pc[2], pc[3], M23);
    m55(pc[5], pc[6], M56);
    m55(pc[7], pc[8], M78);
    m55(pc[9], pc[10], M910);

    f16x2 mA = pair_median(M01,  M23, pc[4]);   // A cols {0,1,2,3}+4
    f16x2 mB = pair_median(M56,  M23, pc[4]);   // B cols {2,3,5,6}+4
    f16x2 mC = pair_median(M56,  M78, pc[4]);   // C cols {5,6,7,8}+4
    f16x2 mD = pair_median(M910, M78, pc[6]);   // D cols {7,8,9,10}+6

    out[2*idx]   = make_float4((float)mA[0], (float)mA[1], (float)mB[0], (float)mB[1]);
    out[2*idx+1] = make_float4((float)mC[0], (float)mC[1], (float)mD[0], (float)mD[1]);
}

extern "C" void kernel_launch(void* const* d_in, const int* in_sizes, int n_in,
                              void* d_out, int out_size, void* d_ws, size_t ws_size,
                              hipStream_t stream) {
    const float* image = (const float*)d_in[0];
    float4* out = (float4*)d_out;
    int nocts = in_sizes[0] / 8;        // 393,216 octets
    int block = 256;
    int grid = (nocts + block - 1) / block;
    median5_o<<<grid, block, 0, stream>>>(image, out, nocts);
}

// Round 11
// 76.571 us; speedup vs baseline: 1.0517x; 1.0001x over previous
//
#include <hip/hip_runtime.h>

// 5x5 median filter, reflect padding, per-channel, [16,3,256,256] f32.
// Round 11: 16 px/lane = 8 wide x 2 output rows (h, h+1).
//   - 6 input rows loaded once (24 float4 vs 40 for two octets, -40% L1 bytes)
//   - per column: sort4 of the 4 shared rows (5 CE) + two merge(4,1) inserts
//     (4 CE each) -> sorted-5 for each row; same sorted sequence as sort5,
//     so output stays bit-identical (absmax 0.00390625).
//   - per row: round-10 merge network (5x m55, 4x pruned m1010 + sel5_65).

#define HH 256
#define WW 256

typedef __fp16 f16x2 __attribute__((ext_vector_type(2)));

__device__ __forceinline__ f16x2 mn(f16x2 a, f16x2 b) { return __builtin_elementwise_min(a, b); }
__device__ __forceinline__ f16x2 mx(f16x2 a, f16x2 b) { return __builtin_elementwise_max(a, b); }

__device__ __forceinline__ void ce(f16x2 &a, f16x2 &b) {
    f16x2 lo = mn(a, b);
    f16x2 hi = mx(a, b);
    a = lo; b = hi;
}

// Batcher odd-even merges of ascending sorted lists (all indices static).
__device__ __forceinline__ void m11(const f16x2* A, const f16x2* B, f16x2* Z) {
    Z[0] = mn(A[0], B[0]); Z[1] = mx(A[0], B[0]);
}

__device__ __forceinline__ void m21(const f16x2* A, const f16x2* B, f16x2* Z) {
    f16x2 E[2]; m11(A, B, E);
    Z[0] = E[0];
    Z[1] = mn(A[1], E[1]); Z[2] = mx(A[1], E[1]);
}

__device__ __forceinline__ void m22(const f16x2* A, const f16x2* B, f16x2* Z) {
    f16x2 e0 = A[0], e1 = B[0]; ce(e0, e1);
    f16x2 o0 = A[1], o1 = B[1]; ce(o0, o1);
    Z[0] = e0; f16x2 p = o0, q = e1; ce(p, q); Z[1] = p; Z[2] = q; Z[3] = o1;
}

__device__ __forceinline__ void m32(const f16x2* A, const f16x2* B, f16x2* Z) {
    f16x2 Ae[2] = {A[0], A[2]}, E[3];
    m21(Ae, B, E);
    f16x2 O[2]; f16x2 Ao[1] = {A[1]}, Bo[1] = {B[1]};
    m11(Ao, Bo, O);
    Z[0] = E[0];
    Z[1] = mn(O[0], E[1]); Z[2] = mx(O[0], E[1]);
    Z[3] = mn(O[1], E[2]); Z[4] = mx(O[1], E[2]);
}

__device__ __forceinline__ void m33(const f16x2* A, const f16x2* B, f16x2* Z) {
    f16x2 Ae[2] = {A[0], A[2]}, Be[2] = {B[0], B[2]}, E[4];
    m22(Ae, Be, E);
    f16x2 o0 = A[1], o1 = B[1]; ce(o0, o1);
    Z[0] = E[0];
    f16x2 p = o0, q = E[1]; ce(p, q); Z[1] = p; Z[2] = q;
    p = o1; q = E[2]; ce(p, q); Z[3] = p; Z[4] = q;
    Z[5] = E[3];
}

__device__ __forceinline__ void m55(const f16x2* A, const f16x2* B, f16x2* Z) {
    f16x2 Ae[3] = {A[0], A[2], A[4]}, Be[3] = {B[0], B[2], B[4]}, E[6];
    m33(Ae, Be, E);
    f16x2 Ao[2] = {A[1], A[3]}, Bo[2] = {B[1], B[3]}, O[4];
    m22(Ao, Bo, O);
    Z[0] = E[0];
#pragma unroll
    for (int i = 0; i < 4; ++i) {
        f16x2 p = O[i], q = E[i+1]; ce(p, q); Z[2*i+1] = p; Z[2*i+2] = q;
    }
    Z[9] = E[5];
}

__device__ __forceinline__ void m1010(const f16x2* S, const f16x2* T, f16x2* Z) {
    f16x2 Se[5] = {S[0],S[2],S[4],S[6],S[8]}, Te[5] = {T[0],T[2],T[4],T[6],T[8]}, E[10];
    m55(Se, Te, E);
    f16x2 So[5] = {S[1],S[3],S[5],S[7],S[9]}, To[5] = {T[1],T[3],T[5],T[7],T[9]}, O[10];
    m55(So, To, O);
    Z[0] = E[0];
#pragma unroll
    for (int i = 0; i < 9; ++i) {
        f16x2 p = O[i], q = E[i+1]; ce(p, q); Z[2*i+1] = p; Z[2*i+2] = q;
    }
    Z[19] = O[9];
}

// rank-5 (0-indexed) of merge(U6 sorted, c5 sorted) == median of the 11.
__device__ __forceinline__ f16x2 sel5_65(const f16x2* U, const f16x2* c) {
    f16x2 Ue[3] = {U[0], U[2], U[4]}, ce_[3] = {c[0], c[2], c[4]}, E[6];
    m33(Ue, ce_, E);
    f16x2 Uo[3] = {U[1], U[3], U[5]}, co[2] = {c[1], c[3]}, O[5];
    m32(Uo, co, O);
    return mn(O[2], E[3]);
}

__device__ __forceinline__ f16x2 pair_median(const f16x2* M, const f16x2* N,
                                             const f16x2* f) {
    f16x2 U[20];
    m1010(M, N, U);                 // only ranks 7..12 survive DCE
    return sel5_65(&U[7], f);
}

// Insert b into sorted-4 A -> sorted-5 Z (Batcher merge(4,1), 4 CEs).
__device__ __forceinline__ void m41(const f16x2* A, f16x2 b, f16x2* Z) {
    f16x2 e0 = mn(A[0], b), t = mx(A[0], b);
    f16x2 e1 = mn(A[2], t), e2 = mx(A[2], t);
    Z[0] = e0;
    Z[1] = mn(A[1], e1); Z[2] = mx(A[1], e1);
    Z[3] = mn(A[3], e2); Z[4] = mx(A[3], e2);
}

__global__ void __launch_bounds__(256) median5_v(const float* __restrict__ in,
                                                 float4* __restrict__ out,
                                                 int nunits) {
    int idx = blockIdx.x * blockDim.x + threadIdx.x;
    if (idx >= nunits) return;

    int u  = idx & 4095;                // 32 octets x 128 row-pairs per plane
    int plane = idx >> 12;
    int w0 = (u & 31) << 3;             // first pixel column
    int hb = (u >> 5) << 1;             // first output row (even)
    const float* p = in + (size_t)plane * (HH * WW);

    int rr[6];
#pragma unroll
    for (int d = 0; d < 6; ++d) {       // input rows hb-2 .. hb+3, reflected
        int r = hb + d - 2;
        r = (r < 0) ? -r : r;
        r = (r >= HH) ? (2*HH - 2 - r) : r;
        rr[d] = r * WW;
    }

    const bool left  = (w0 == 0);
    const bool right = (w0 == WW - 8);
    const int b0base = left  ? 0        : (w0 - 4);
    const int b3base = right ? (WW - 4) : (w0 + 8);

    // pc[j][d]: packed column j (pk of input cols w0-2+j, w0-1+j), input row d.
    f16x2 pc[11][6];
#pragma unroll
    for (int d = 0; d < 6; ++d) {
        const float* prow = p + rr[d];
        float4 b0 = *(const float4*)(prow + b0base);
        float4 b1 = *(const float4*)(prow + w0);
        float4 b2 = *(const float4*)(prow + w0 + 4);
        float4 b3 = *(const float4*)(prow + b3base);
        float x0  = b0.z;
        float x1  = left  ? b0.y : b0.w;
        float x2  = b1.x, x3 = b1.y, x4 = b1.z, x5 = b1.w;
        float x6  = b2.x, x7 = b2.y, x8 = b2.z, x9 = b2.w;
        float x10 = right ? b3.z : b3.x;
        float x11 = b3.y;
        pc[0][d]  = __builtin_amdgcn_cvt_pkrtz(x0, x1);
        pc[1][d]  = __builtin_amdgcn_cvt_pkrtz(x1, x2);
        pc[2][d]  = __builtin_amdgcn_cvt_pkrtz(x2, x3);
        pc[3][d]  = __builtin_amdgcn_cvt_pkrtz(x3, x4);
        pc[4][d]  = __builtin_amdgcn_cvt_pkrtz(x4, x5);
        pc[5][d]  = __builtin_amdgcn_cvt_pkrtz(x5, x6);
        pc[6][d]  = __builtin_amdgcn_cvt_pkrtz(x6, x7);
        pc[7][d]  = __builtin_amdgcn_cvt_pkrtz(x7, x8);
        pc[8][d]  = __builtin_amdgcn_cvt_pkrtz(x8, x9);
        pc[9][d]  = __builtin_amdgcn_cvt_pkrtz(x9, x10);
        pc[10][d] = __builtin_amdgcn_cvt_pkrtz(x10, x11);
    }

    // Shared vertical sort: sort4 of common rows d=1..4, then insert d=0
    // (row window h-2..h+2) and d=5 (h-1..h+3).
    f16x2 sA[11][5], sB[11][5];
#pragma unroll
    for (int j = 0; j < 11; ++j) {
        f16x2 a = pc[j][1], b = pc[j][2], c = pc[j][3], d = pc[j][4];
        ce(a,b); ce(c,d); ce(a,c); ce(b,d); ce(b,c);   // sort4, 5 CE
        f16x2 s4[4] = {a, b, c, d};
        m41(s4, pc[j][0], sA[j]);
        m41(s4, pc[j][5], sB[j]);
    }

    size_t o = ((size_t)plane * HH + hb) * (WW/4) + (w0 >> 2);

    {   // output row hb
        f16x2 M01[10], M23[10], M56[10], M78[10], M910[10];
        m55(sA[0], sA[1], M01);
        m55(sA[2], sA[3], M23);
        m55(sA[5], sA[6], M56);
        m55(sA[7], sA[8], M78);
        m55(sA[9], sA[10], M910);
        f16x2 mA = pair_median(M01,  M23, sA[4]);
        f16x2 mB = pair_median(M56,  M23, sA[4]);
        f16x2 mC = pair_median(M56,  M78, sA[4]);
        f16x2 mD = pair_median(M910, M78, sA[6]);
        out[o]     = make_float4((float)mA[0], (float)mA[1], (float)mB[0], (float)mB[1]);
        out[o + 1] = make_float4((float)mC[0], (float)mC[1], (float)mD[0], (float)mD[1]);
    }
    {   // output row hb+1
        f16x2 M01[10], M23[10], M56[10], M78[10], M910[10];
        m55(sB[0], sB[1], M01);
        m55(sB[2], sB[3], M23);
        m55(sB[5], sB[6], M56);
        m55(sB[7], sB[8], M78);
        m55(sB[9], sB[10], M910);
        f16x2 mA = pair_median(M01,  M23, sB[4]);
        f16x2 mB = pair_median(M56,  M23, sB[4]);
        f16x2 mC = pair_median(M56,  M78, sB[4]);
        f16x2 mD = pair_median(M910, M78, sB[6]);
        size_t o2 = o + (WW/4);
        out[o2]     = make_float4((float)mA[0], (float)mA[1], (float)mB[0], (float)mB[1]);
        out[o2 + 1] = make_float4((float)mC[0], (float)mC[1], (float)mD[0], (float)mD[1]);
    }
}

extern "C" void kernel_launch(void* const* d_in, const int* in_sizes, int n_in,
                              void* d_out, int out_size, void* d_ws, size_t ws_size,
                              hipStream_t stream) {
    const float* image = (const float*)d_in[0];
    float4* out = (float4*)d_out;
    int nunits = in_sizes[0] / 16;      // 196,608 units (8 wide x 2 rows)
    int block = 256;
    int grid = (nunits + block - 1) / block;
    median5_v<<<grid, block, 0, stream>>>(image, out, nunits);
}